// Round 12
// baseline (393.021 us; speedup 1.0000x reference)
//
#include <hip/hip_runtime.h>
#include <hip/hip_bf16.h>
#include <math.h>

// ChunkedLinearCrossEntropyLoss fused kernel for MI355X (gfx950) — R12
//
// hidden[4096,2048] f32, weight[32768,2048] f32, targets[4096] i32 -> scalar
//
//  Kc  convert_fp8  : f32 -> fp8 e4m3 copies (natural k order)
//  K0  target_logit : x_t[row] = softcap(h[row].w[tgt[row]]) fp32 (exact)
//  K1  gemm_mx      : R11's 256x256 / 8-wave / BK=128 pipeline + inline-asm
//                     MFMA ("+a" acc). R12: LDS layout [khalf][256][64B]
//                     (64B half-rows) with R7's verified slot swizzle
//                     phys = logical ^ ((row>>1)&3): bank = 16*(row&1) +
//                     4*slot — R7 counted 0 conflicts with this pattern;
//                     128B rows (R8-R11) cost 4 cyc/ds_read (2.5e7 counter).
//  K2  row_reduce   : sum column-block partials per row
//  K3  final_reduce : scalar loss

#define N_ROWS 4096
#define DIM    2048
#define VOCAB  32768
#define IGNORE_IDX (-100)

#define BM 256
#define BN 256
#define BK 128
#define NT (DIM / BK)            // 16 K-tiles
#define NCB (VOCAB / BN)         // 128 column blocks
#define ROW_TILES (N_ROWS / BM)  // 16

typedef short s16x8 __attribute__((ext_vector_type(8)));
typedef unsigned short u16x8 __attribute__((ext_vector_type(8)));
typedef float f32x4 __attribute__((ext_vector_type(4)));
typedef int   i32x4 __attribute__((ext_vector_type(4)));
typedef int   i32x8 __attribute__((ext_vector_type(8)));

#define AS3(p) ((__attribute__((address_space(3))) void*)(p))
#define AS1(p) ((const __attribute__((address_space(1))) void*)(p))

// Non-scaled f8f6f4 MFMA (cbsz/blgp=0 -> fp8 e4m3 A and B, scale=1.0).
// "+a" pins the accumulator quad in AGPRs (fixed the R8-R10 spill).
#define MFMA_F8(accv, a, b)                                                   \
    asm volatile("v_mfma_f32_16x16x128_f8f6f4 %0, %1, %2, %0"                 \
                 : "+a"(accv) : "v"(a), "v"(b))

// 20*tanh(x/20) via hardware exp; clamp keeps exp finite for any input.
__device__ __forceinline__ float softcap(float x) {
    x = fminf(80.f, fmaxf(-80.f, x));
    float e = __expf(x * 0.1f);
    return 20.f * (e - 1.f) * __builtin_amdgcn_rcpf(e + 1.f);
}

// f32 -> bf16 RNE (fallback path only)
__device__ __forceinline__ unsigned short f2bf(float f) {
    union { float f; unsigned u; } v; v.f = f;
    unsigned r = v.u + 0x7FFFu + ((v.u >> 16) & 1u);
    return (unsigned short)(r >> 16);
}

// ---------------------------------------------------------------------------
// Kc: f32 -> fp8 e4m3, natural (linear) k order. One thread = 16 elems.
// ---------------------------------------------------------------------------
__global__ __launch_bounds__(256) void convert_fp8(
    const float* __restrict__ src, unsigned char* __restrict__ dst, int nchunk)
{
    int idx = blockIdx.x * 256 + threadIdx.x;
    int stride = gridDim.x * 256;
    for (int i = idx; i < nchunk; i += stride) {
        const float* p = src + (size_t)i * 16;
        float4 a0 = *(const float4*)(p);
        float4 a1 = *(const float4*)(p + 4);
        float4 b0 = *(const float4*)(p + 8);
        float4 b1 = *(const float4*)(p + 12);
        int w0 = __builtin_amdgcn_cvt_pk_fp8_f32(a0.x, a0.y, 0, false);
        w0     = __builtin_amdgcn_cvt_pk_fp8_f32(a0.z, a0.w, w0, true);
        int w1 = __builtin_amdgcn_cvt_pk_fp8_f32(a1.x, a1.y, 0, false);
        w1     = __builtin_amdgcn_cvt_pk_fp8_f32(a1.z, a1.w, w1, true);
        int w2 = __builtin_amdgcn_cvt_pk_fp8_f32(b0.x, b0.y, 0, false);
        w2     = __builtin_amdgcn_cvt_pk_fp8_f32(b0.z, b0.w, w2, true);
        int w3 = __builtin_amdgcn_cvt_pk_fp8_f32(b1.x, b1.y, 0, false);
        w3     = __builtin_amdgcn_cvt_pk_fp8_f32(b1.z, b1.w, w3, true);
        *(int4*)(dst + (size_t)i * 16) = make_int4(w0, w1, w2, w3);
    }
}

// ---------------------------------------------------------------------------
// K0: x_t[row] = softcap(dot(hidden[row], weight[tgt])) fp32. 1 wave/row.
// ---------------------------------------------------------------------------
__global__ __launch_bounds__(256) void target_logit(
    const float* __restrict__ hidden, const float* __restrict__ weight,
    const int* __restrict__ targets, float* __restrict__ xtbuf)
{
    int row  = blockIdx.x * 4 + (threadIdx.x >> 6);
    int lane = threadIdx.x & 63;
    if (row >= N_ROWS) return;
    int tgt = targets[row];
    if (tgt < 0 || tgt >= VOCAB) {
        if (lane == 0) xtbuf[row] = 0.f;
        return;
    }
    const float4* h4 = (const float4*)(hidden + (size_t)row * DIM);
    const float4* w4 = (const float4*)(weight + (size_t)tgt * DIM);
    float d = 0.f;
#pragma unroll
    for (int j = 0; j < DIM / 4 / 64; j++) {
        float4 a = h4[lane + 64 * j];
        float4 b = w4[lane + 64 * j];
        d += a.x * b.x + a.y * b.y + a.z * b.z + a.w * b.w;
    }
#pragma unroll
    for (int off = 1; off < 64; off <<= 1) d += __shfl_xor(d, off, 64);
    if (lane == 0) xtbuf[row] = softcap(d);
}

// ---------------------------------------------------------------------------
// K1: 256x256 8-wave fp8 GEMM at MX rate (K=128/MFMA), 2 windows/tile.
//
// LDS (129+1 KB): Abuf[2] @ {0,32K}, Bbuf[2] @ {64K,96K}, dummy @128K.
// Buffer layout: [khalf:2 x16K][row:256 x64][slot:4 x16]. A lane's 32B
// fragment (k = g*32+[0,32)) = slots {(2g)&3,(2g+1)&3} of khalf g>>1.
// Swizzle (R7-verified): phys slot = logical ^ ((row>>1)&3); read bank =
// 16*(row&1) + 4*physslot -> 8 (parity,slot) combos x 4 banks = 32 banks,
// 2 words/bank. Stager inverse-permutes the global SOURCE; LDS dest linear.
//
// Chunks = 64 tile-rows, 1 global_load_lds/wave: wave w covers khalf w&1,
// rows ci*64 + (w>>1)*16 + [0,16), 4 lanes/row.
// Schedule (= R9/R11, verified): W0 (acc[0..3]) reads A a(2wr) + all B,
// issues (t+1, a1,a3) -> other buf, vmcnt(8). W1 (acc[4..7]) reads A
// a(2wr+1), issues (t+2, b0-3,a0,a2) -> current buf (reads retired in W0),
// vmcnt(8). Prologue 14 issues + vmcnt(8). ct>=NT -> dummy (counts exact).
// ---------------------------------------------------------------------------
__device__ __forceinline__ void stage_mx(
    int isB, int ci, int ct, const unsigned char* Asrc, const unsigned char* Bsrc,
    unsigned char* smem, int w, int laneoff)
{
    const int kcol = (ct & (NT - 1)) * BK + (w & 1) * 64;     // khalf per wave
    const int row0 = ci * 64 + (w >> 1) * 16;                 // 16 rows/wave
    const int base = (isB ? 65536 : 0) + (ct & 1) * 32768 + (w & 1) * 16384;
    const int dest = (ct >= NT) ? 131072 : base + row0 * 64;
    const unsigned char* src = (isB ? Bsrc : Asrc) + (size_t)row0 * DIM + kcol + laneoff;
    __builtin_amdgcn_global_load_lds(AS1(src), AS3(smem + dest), 16, 0, 0);
}

// two ds_read_b128 (one per 16B slot) -> one 8-reg tuple
#define LDFRAG(buf, row)                                                       \
    __builtin_shufflevector(*(const i32x4*)((buf) + (row) * 64 + colx0),       \
                            *(const i32x4*)((buf) + (row) * 64 + colx1),       \
                            0, 1, 2, 3, 4, 5, 6, 7)

__global__ __launch_bounds__(512, 2) void gemm_mx(
    const unsigned char* __restrict__ A, const unsigned char* __restrict__ B,
    float2* __restrict__ part)
{
    __shared__ unsigned char smem[131072 + 1024] __attribute__((aligned(16)));

    const int bid  = blockIdx.x;
    const int brow = bid & (ROW_TILES - 1);   // 16 consecutive blocks share B panel
    const int bcol = bid >> 4;
    const int t0   = threadIdx.x;
    const int lane = t0 & 63;
    const int w    = t0 >> 6;                 // 0..7
    const int wr   = w >> 2;                  // 0..1 (M)
    const int wc   = w & 3;                   // 0..3 (N)
    const int li   = lane & 15;
    const int g    = lane >> 4;               // 0..3 (k-group: k = g*32+[0,32))

    // fragment read offsets: khalf g>>1, logical slots (2g)&3 / (2g+1)&3,
    // phys = logical ^ ((li>>1)&3)  (row ≡ li mod 16, row>>1&3 = li>>1&3)
    const int sw    = (li >> 1) & 3;
    const int colx0 = (g >> 1) * 16384 + ((((2 * g)     & 3) ^ sw) << 4);
    const int colx1 = (g >> 1) * 16384 + ((((2 * g + 1) & 3) ^ sw) << 4);

    // staging source (inverse swizzle): lane l covers half-row l>>2,
    // phys slot l&3 -> logical slot (l&3) ^ ((l>>3)&3).
    const int laneoff = (lane >> 2) * DIM + (((lane & 3) ^ ((lane >> 3) & 3)) << 4);

    const unsigned char* Asrc = A + (size_t)brow * BM * DIM;
    const unsigned char* Bsrc = B + (size_t)bcol * BN * DIM;

    f32x4 acc[8][4];
#pragma unroll
    for (int m = 0; m < 8; m++)
#pragma unroll
        for (int n = 0; n < 4; n++) acc[m][n] = (f32x4){0.f, 0.f, 0.f, 0.f};

    // ---- prologue: 14 issues; vmcnt(8) confirms tile0 {b0-3, a0, a2} ----
    stage_mx(1, 0, 0, Asrc, Bsrc, smem, w, laneoff);
    stage_mx(1, 1, 0, Asrc, Bsrc, smem, w, laneoff);
    stage_mx(1, 2, 0, Asrc, Bsrc, smem, w, laneoff);
    stage_mx(1, 3, 0, Asrc, Bsrc, smem, w, laneoff);
    stage_mx(0, 0, 0, Asrc, Bsrc, smem, w, laneoff);
    stage_mx(0, 2, 0, Asrc, Bsrc, smem, w, laneoff);
    stage_mx(0, 1, 0, Asrc, Bsrc, smem, w, laneoff);
    stage_mx(0, 3, 0, Asrc, Bsrc, smem, w, laneoff);
    stage_mx(1, 0, 1, Asrc, Bsrc, smem, w, laneoff);
    stage_mx(1, 1, 1, Asrc, Bsrc, smem, w, laneoff);
    stage_mx(1, 2, 1, Asrc, Bsrc, smem, w, laneoff);
    stage_mx(1, 3, 1, Asrc, Bsrc, smem, w, laneoff);
    stage_mx(0, 0, 1, Asrc, Bsrc, smem, w, laneoff);
    stage_mx(0, 2, 1, Asrc, Bsrc, smem, w, laneoff);
    asm volatile("s_waitcnt vmcnt(8)" ::: "memory");
    __builtin_amdgcn_s_barrier();
    __builtin_amdgcn_sched_barrier(0);

    i32x8 bfr[4];

    for (int t = 0; t < NT; ++t) {
        const int b = t & 1;
        unsigned char* A_rd = smem + b * 32768;
        unsigned char* B_rd = smem + 65536 + b * 32768;

        // ---------------- window 0: acc[0..3] ----------------
        {
#pragma unroll
            for (int n = 0; n < 4; n++)
                bfr[n] = LDFRAG(B_rd, wc * 64 + n * 16 + li);
            stage_mx(0, 1, t + 1, Asrc, Bsrc, smem, w, laneoff);
            stage_mx(0, 3, t + 1, Asrc, Bsrc, smem, w, laneoff);
            __builtin_amdgcn_s_setprio(1);
#pragma unroll
            for (int m = 0; m < 4; m++) {
                i32x8 afr = LDFRAG(A_rd, wr * 128 + m * 16 + li);
                MFMA_F8(acc[m][0], afr, bfr[0]);
                MFMA_F8(acc[m][1], afr, bfr[1]);
                MFMA_F8(acc[m][2], afr, bfr[2]);
                MFMA_F8(acc[m][3], afr, bfr[3]);
            }
            __builtin_amdgcn_s_setprio(0);
            asm volatile("s_waitcnt vmcnt(8)" ::: "memory");
            __builtin_amdgcn_s_barrier();
            __builtin_amdgcn_sched_barrier(0);
        }
        // ---------------- window 1: acc[4..7] ----------------
        {
            stage_mx(1, 0, t + 2, Asrc, Bsrc, smem, w, laneoff);
            stage_mx(1, 1, t + 2, Asrc, Bsrc, smem, w, laneoff);
            stage_mx(1, 2, t + 2, Asrc, Bsrc, smem, w, laneoff);
            stage_mx(1, 3, t + 2, Asrc, Bsrc, smem, w, laneoff);
            stage_mx(0, 0, t + 2, Asrc, Bsrc, smem, w, laneoff);
            stage_mx(0, 2, t + 2, Asrc, Bsrc, smem, w, laneoff);
            __builtin_amdgcn_s_setprio(1);
#pragma unroll
            for (int m = 0; m < 4; m++) {
                i32x8 afr = LDFRAG(A_rd, wr * 128 + 64 + m * 16 + li);
                MFMA_F8(acc[m + 4][0], afr, bfr[0]);
                MFMA_F8(acc[m + 4][1], afr, bfr[1]);
                MFMA_F8(acc[m + 4][2], afr, bfr[2]);
                MFMA_F8(acc[m + 4][3], afr, bfr[3]);
            }
            __builtin_amdgcn_s_setprio(0);
            asm volatile("s_waitcnt vmcnt(8)" ::: "memory");
            __builtin_amdgcn_s_barrier();
            __builtin_amdgcn_sched_barrier(0);
        }
    }

    // ---- epilogue: per-row (sum_exp, sum_logit) over 256 columns ----
    __syncthreads();   // full drain (also retires dummy wrap prefetches)
    // MFMA -> accvgpr_read hazard guard (compiler can't see through the asm)
    asm volatile("s_nop 7\n\ts_nop 7\n\ts_nop 7" :::);
    float* red = (float*)smem;   // [8][128][2] f32 = 8 KB, aliases Abuf0

#pragma unroll
    for (int m = 0; m < 8; m++) {
#pragma unroll
        for (int r = 0; r < 4; r++) {
            float s0 = softcap(acc[m][0][r]);
            float s1 = softcap(acc[m][1][r]);
            float s2 = softcap(acc[m][2][r]);
            float s3 = softcap(acc[m][3][r]);
            float se = __expf(s0) + __expf(s1) + __expf(s2) + __expf(s3);
            float st = s0 + s1 + s2 + s3;
#pragma unroll
            for (int off = 1; off < 16; off <<= 1) {
                se += __shfl_xor(se, off, 64);
                st += __shfl_xor(st, off, 64);
            }
            if (li == 0) {
                int rl = m * 16 + g * 4 + r;          // row within wave's 128
                int base = ((wr * 4 + wc) * 128 + rl) * 2;
                red[base + 0] = se;
                red[base + 1] = st;
            }
        }
    }
    __syncthreads();
    if (t0 < BM) {
        int r   = t0;
        int wr2 = r >> 7;
        int rr  = r & 127;
        float se = 0.f, st = 0.f;
#pragma unroll
        for (int q = 0; q < 4; q++) {
            int bq = ((wr2 * 4 + q) * 128 + rr) * 2;
            se += red[bq + 0];
            st += red[bq + 1];
        }
        part[(size_t)(brow * BM + r) * NCB + bcol] = make_float2(se, st);
    }
}

// ---------------------------------------------------------------------------
// K1 fallback (small ws): reg-staged f32->bf16, 128x128, BK=32.
// ---------------------------------------------------------------------------
__global__ __launch_bounds__(256) void gemm_partial_f32(
    const float* __restrict__ hidden, const float* __restrict__ weight,
    float2* __restrict__ part)
{
    __shared__ unsigned short sA[128 * 32];
    __shared__ unsigned short sB[128 * 32];
    __shared__ float red[4][64][2];

    const int bid  = blockIdx.x;
    const int brow = bid & 31;
    const int bcol = bid >> 5;
    const int t    = threadIdx.x;
    const int lane = t & 63;
    const int w    = t >> 6;
    const int wr   = w >> 1, wc = w & 1;

    const int srow = t >> 1;
    const int scol = (t & 1) * 16;
    const float* gA = hidden + (size_t)(brow * 128 + srow) * DIM + scol;
    const float* gB = weight + (size_t)(bcol * 128 + srow) * DIM + scol;
    unsigned short* wA = &sA[srow * 32 + scol];
    unsigned short* wB = &sB[srow * 32 + scol];

    f32x4 acc[4][4];
#pragma unroll
    for (int m = 0; m < 4; m++)
#pragma unroll
        for (int n = 0; n < 4; n++) acc[m][n] = (f32x4){0.f, 0.f, 0.f, 0.f};

    const unsigned short* pa = &sA[(wr * 64 + (lane & 15)) * 32 + (lane >> 4) * 8];
    const unsigned short* pb = &sB[(wc * 64 + (lane & 15)) * 32 + (lane >> 4) * 8];

    for (int k0 = 0; k0 < DIM; k0 += 32) {
        float4 a0 = *(const float4*)(gA + k0);
        float4 a1 = *(const float4*)(gA + k0 + 4);
        float4 a2 = *(const float4*)(gA + k0 + 8);
        float4 a3 = *(const float4*)(gA + k0 + 12);
        float4 b0 = *(const float4*)(gB + k0);
        float4 b1 = *(const float4*)(gB + k0 + 4);
        float4 b2 = *(const float4*)(gB + k0 + 8);
        float4 b3 = *(const float4*)(gB + k0 + 12);
        __syncthreads();
        u16x8 pa0 = { f2bf(a0.x), f2bf(a0.y), f2bf(a0.z), f2bf(a0.w),
                      f2bf(a1.x), f2bf(a1.y), f2bf(a1.z), f2bf(a1.w) };
        u16x8 pa1 = { f2bf(a2.x), f2bf(a2.y), f2bf(a2.z), f2bf(a2.w),
                      f2bf(a3.x), f2bf(a3.y), f2bf(a3.z), f2bf(a3.w) };
        u16x8 pb0 = { f2bf(b0.x), f2bf(b0.y), f2bf(b0.z), f2bf(b0.w),
                      f2bf(b1.x), f2bf(b1.y), f2bf(b1.z), f2bf(b1.w) };
        u16x8 pb1 = { f2bf(b2.x), f2bf(b2.y), f2bf(b2.z), f2bf(b2.w),
                      f2bf(b3.x), f2bf(b3.y), f2bf(b3.z), f2bf(b3.w) };
        *(u16x8*)wA = pa0;
        *(u16x8*)(wA + 8) = pa1;
        *(u16x8*)wB = pb0;
        *(u16x8*)(wB + 8) = pb1;
        __syncthreads();

        s16x8 afr[4], bfr[4];
#pragma unroll
        for (int m = 0; m < 4; m++) afr[m] = *(const s16x8*)(pa + m * 16 * 32);
#pragma unroll
        for (int n = 0; n < 4; n++) bfr[n] = *(const s16x8*)(pb + n * 16 * 32);
#pragma unroll
        for (int m = 0; m < 4; m++)
#pragma unroll
            for (int n = 0; n < 4; n++)
                acc[m][n] = __builtin_amdgcn_mfma_f32_16x16x32_bf16(
                    afr[m], bfr[n], acc[m][n], 0, 0, 0);
    }

    const int g  = lane >> 4;
    const int li = lane & 15;
#pragma unroll
    for (int m = 0; m < 4; m++) {
#pragma unroll
        for (int r = 0; r < 4; r++) {
            float s0 = softcap(acc[m][0][r]);
            float s1 = softcap(acc[m][1][r]);
            float s2 = softcap(acc[m][2][r]);
            float s3 = softcap(acc[m][3][r]);
            float se = __expf(s0) + __expf(s1) + __expf(s2) + __expf(s3);
            float st = s0 + s1 + s2 + s3;
#pragma unroll
            for (int off = 1; off < 16; off <<= 1) {
                se += __shfl_xor(se, off, 64);
                st += __shfl_xor(st, off, 64);
            }
            if (li == 0) {
                int rl = m * 16 + g * 4 + r;
                red[w][rl][0] = se;
                red[w][rl][1] = st;
            }
        }
    }
    __syncthreads();
    if (t < 128) {
        int r  = t;
        int wa = (r >> 6) * 2;
        int rr = r & 63;
        float se = red[wa][rr][0] + red[wa + 1][rr][0];
        float st = red[wa][rr][1] + red[wa + 1][rr][1];
        part[(size_t)(brow * 128 + r) * 256 + bcol] = make_float2(se, st);
    }
}

// ---------------------------------------------------------------------------
// K2: sum ncb column-block partials per row. 1 wave/row.
// ---------------------------------------------------------------------------
__global__ __launch_bounds__(256) void row_reduce(
    const float2* __restrict__ part, const int* __restrict__ targets,
    const float* __restrict__ xtbuf, float* __restrict__ rowbuf, int ncb)
{
    int row  = blockIdx.x * 4 + (threadIdx.x >> 6);
    int lane = threadIdx.x & 63;
    if (row >= N_ROWS) return;
    const float2* p = part + (size_t)row * ncb;
    float se = 0.f, st = 0.f;
    for (int q = lane; q < ncb; q += 64) {
        float2 u = p[q];
        se += u.x;
        st += u.y;
    }
#pragma unroll
    for (int off = 1; off < 64; off <<= 1) {
        se += __shfl_xor(se, off, 64);
        st += __shfl_xor(st, off, 64);
    }
    if (lane == 0) {
        float lse = logf(se);
        int   tgt = targets[row];
        float vf  = (tgt != IGNORE_IDX) ? 1.f : 0.f;
        float xt  = xtbuf[row];
        float nll = lse - xt;
        float smooth = lse - st * (1.f / (float)VOCAB);
        float rl = 0.9f * nll + 0.1f * smooth;
        rowbuf[row * 3 + 0] = rl * vf;
        rowbuf[row * 3 + 1] = lse * lse * vf;
        rowbuf[row * 3 + 2] = vf;
    }
}

// ---------------------------------------------------------------------------
// K3: deterministic final reduction -> scalar loss.
// ---------------------------------------------------------------------------
__global__ __launch_bounds__(256) void final_reduce(
    const float* __restrict__ rowbuf, float* __restrict__ out)
{
    __shared__ float sl[256], sz[256], sv[256];
    int t = threadIdx.x;
    float ls = 0.f, zs = 0.f, vs = 0.f;
    for (int r = t; r < N_ROWS; r += 256) {
        ls += rowbuf[r * 3 + 0];
        zs += rowbuf[r * 3 + 1];
        vs += rowbuf[r * 3 + 2];
    }
    sl[t] = ls; sz[t] = zs; sv[t] = vs;
    __syncthreads();
    for (int o = 128; o > 0; o >>= 1) {
        if (t < o) { sl[t] += sl[t + o]; sz[t] += sz[t + o]; sv[t] += sv[t + o]; }
        __syncthreads();
    }
    if (t == 0) {
        float nv = fmaxf(sv[0], 1.f);
        out[0] = sl[0] / nv + 1e-4f * (sz[0] / nv);
    }
}

// ---------------------------------------------------------------------------
extern "C" void kernel_launch(void* const* d_in, const int* in_sizes, int n_in,
                              void* d_out, int out_size, void* d_ws, size_t ws_size,
                              hipStream_t stream)
{
    const float* hidden  = (const float*)d_in[0];
    const float* weight  = (const float*)d_in[1];
    const int*   targets = (const int*)d_in[2];
    float*       out     = (float*)d_out;

    char* ws = (char*)d_ws;
    size_t off = 0;
    float2* part = (float2*)(ws + off);
    off += (size_t)N_ROWS * 256 * sizeof(float4);           // 16 MB slot (max layout)
    float* xtbuf = (float*)(ws + off);
    off += (size_t)N_ROWS * sizeof(float);
    float* rowbuf = (float*)(ws + off);
    off += (size_t)N_ROWS * 3 * sizeof(float);
    off = (off + 255) & ~(size_t)255;
    unsigned char* hid8 = (unsigned char*)(ws + off);
    off += (size_t)N_ROWS * DIM;                            // 8 MB
    unsigned char* wgt8 = (unsigned char*)(ws + off);
    off += (size_t)VOCAB * DIM;                             // 67 MB

    target_logit<<<N_ROWS / 4, 256, 0, stream>>>(hidden, weight, targets, xtbuf);

    if (ws_size >= off) {
        convert_fp8<<<2048, 256, 0, stream>>>(hidden, hid8, N_ROWS * (DIM / 16));
        convert_fp8<<<2048, 256, 0, stream>>>(weight, wgt8, VOCAB * (DIM / 16));
        gemm_mx<<<ROW_TILES * (VOCAB / BN), 512, 0, stream>>>(hid8, wgt8, part);
        row_reduce<<<N_ROWS / 4, 256, 0, stream>>>(part, targets, xtbuf, rowbuf, NCB);
    } else {
        gemm_partial_f32<<<32 * 256, 256, 0, stream>>>(hidden, weight, part);
        row_reduce<<<N_ROWS / 4, 256, 0, stream>>>(part, targets, xtbuf, rowbuf, 256);
    }

    final_reduce<<<1, 256, 0, stream>>>(rowbuf, out);
}

// Round 13
// 381.194 us; speedup vs baseline: 1.0310x; 1.0310x over previous
//
#include <hip/hip_runtime.h>
#include <hip/hip_bf16.h>
#include <math.h>

// ChunkedLinearCrossEntropyLoss fused kernel for MI355X (gfx950) — R13
//
// hidden[4096,2048] f32, weight[32768,2048] f32, targets[4096] i32 -> scalar
//
//  Kc  convert_fp8  : f32 -> fp8 e4m3, K-PERMUTED per 128B K-tile window:
//                     byte layout [khalf:2][slot:4][16B] where khalf0 slot j
//                     = k[j*32, j*32+16), khalf1 slot j = k[j*32+16, j*32+32)
//  K0  target_logit : x_t[row] = softcap(h[row].w[tgt[row]]) fp32 (exact)
//  K1  gemm_mx      : R11/R12 pipeline (inline-asm MFMA, "+a" acc). R13:
//                     fragment read #1 = ALL lanes in khalf0 (slot g^sw),
//                     read #2 = all lanes in khalf1 — byte-identical
//                     lane->bank geometry to R7's measured-ZERO pattern
//                     (R12 split khalves across wave halves -> 16384%128==0
//                     aliasing -> 4 cyc/read, the invariant 2.517e7).
//                     + T1 XCD swizzle (16 blocks sharing a B panel -> 1 L2).
//  K2  row_reduce   : sum column-block partials per row
//  K3  final_reduce : scalar loss

#define N_ROWS 4096
#define DIM    2048
#define VOCAB  32768
#define IGNORE_IDX (-100)

#define BM 256
#define BN 256
#define BK 128
#define NT (DIM / BK)            // 16 K-tiles
#define NCB (VOCAB / BN)         // 128 column blocks
#define ROW_TILES (N_ROWS / BM)  // 16

typedef short s16x8 __attribute__((ext_vector_type(8)));
typedef unsigned short u16x8 __attribute__((ext_vector_type(8)));
typedef float f32x4 __attribute__((ext_vector_type(4)));
typedef int   i32x4 __attribute__((ext_vector_type(4)));
typedef int   i32x8 __attribute__((ext_vector_type(8)));

#define AS3(p) ((__attribute__((address_space(3))) void*)(p))
#define AS1(p) ((const __attribute__((address_space(1))) void*)(p))

// Non-scaled f8f6f4 MFMA (cbsz/blgp=0 -> fp8 e4m3, scale=1.0).
// "+a" pins the accumulator quad in AGPRs (fixed the R8-R10 spill).
#define MFMA_F8(accv, a, b)                                                   \
    asm volatile("v_mfma_f32_16x16x128_f8f6f4 %0, %1, %2, %0"                 \
                 : "+a"(accv) : "v"(a), "v"(b))

// 20*tanh(x/20) via hardware exp; clamp keeps exp finite for any input.
__device__ __forceinline__ float softcap(float x) {
    x = fminf(80.f, fmaxf(-80.f, x));
    float e = __expf(x * 0.1f);
    return 20.f * (e - 1.f) * __builtin_amdgcn_rcpf(e + 1.f);
}

// f32 -> bf16 RNE (fallback path only)
__device__ __forceinline__ unsigned short f2bf(float f) {
    union { float f; unsigned u; } v; v.f = f;
    unsigned r = v.u + 0x7FFFu + ((v.u >> 16) & 1u);
    return (unsigned short)(r >> 16);
}

// ---------------------------------------------------------------------------
// Kc: f32 -> fp8 e4m3 with per-K-tile khalf/slot permutation.
// Piece (row, kt, h, slot): dst 16B at row*DIM + kt*128 + h*64 + slot*16
//                           src k  = kt*128 + slot*32 + h*16 + [0,16)
// ---------------------------------------------------------------------------
__global__ __launch_bounds__(256) void convert_fp8(
    const float* __restrict__ src, unsigned char* __restrict__ dst, int nchunk)
{
    int idx = blockIdx.x * 256 + threadIdx.x;
    int stride = gridDim.x * 256;
    for (int i = idx; i < nchunk; i += stride) {
        int row  = i >> 7;
        int c    = i & 127;
        int kt   = c >> 3;
        int p    = c & 7;
        int h    = p & 1;
        int slot = p >> 1;
        const float* s = src + (size_t)row * DIM + kt * 128 + slot * 32 + h * 16;
        float4 a0 = *(const float4*)(s);
        float4 a1 = *(const float4*)(s + 4);
        float4 b0 = *(const float4*)(s + 8);
        float4 b1 = *(const float4*)(s + 12);
        int w0 = __builtin_amdgcn_cvt_pk_fp8_f32(a0.x, a0.y, 0, false);
        w0     = __builtin_amdgcn_cvt_pk_fp8_f32(a0.z, a0.w, w0, true);
        int w1 = __builtin_amdgcn_cvt_pk_fp8_f32(a1.x, a1.y, 0, false);
        w1     = __builtin_amdgcn_cvt_pk_fp8_f32(a1.z, a1.w, w1, true);
        int w2 = __builtin_amdgcn_cvt_pk_fp8_f32(b0.x, b0.y, 0, false);
        w2     = __builtin_amdgcn_cvt_pk_fp8_f32(b0.z, b0.w, w2, true);
        int w3 = __builtin_amdgcn_cvt_pk_fp8_f32(b1.x, b1.y, 0, false);
        w3     = __builtin_amdgcn_cvt_pk_fp8_f32(b1.z, b1.w, w3, true);
        *(int4*)(dst + (size_t)row * DIM + kt * 128 + h * 64 + slot * 16) =
            make_int4(w0, w1, w2, w3);
    }
}

// ---------------------------------------------------------------------------
// K0: x_t[row] = softcap(dot(hidden[row], weight[tgt])) fp32. 1 wave/row.
// ---------------------------------------------------------------------------
__global__ __launch_bounds__(256) void target_logit(
    const float* __restrict__ hidden, const float* __restrict__ weight,
    const int* __restrict__ targets, float* __restrict__ xtbuf)
{
    int row  = blockIdx.x * 4 + (threadIdx.x >> 6);
    int lane = threadIdx.x & 63;
    if (row >= N_ROWS) return;
    int tgt = targets[row];
    if (tgt < 0 || tgt >= VOCAB) {
        if (lane == 0) xtbuf[row] = 0.f;
        return;
    }
    const float4* h4 = (const float4*)(hidden + (size_t)row * DIM);
    const float4* w4 = (const float4*)(weight + (size_t)tgt * DIM);
    float d = 0.f;
#pragma unroll
    for (int j = 0; j < DIM / 4 / 64; j++) {
        float4 a = h4[lane + 64 * j];
        float4 b = w4[lane + 64 * j];
        d += a.x * b.x + a.y * b.y + a.z * b.z + a.w * b.w;
    }
#pragma unroll
    for (int off = 1; off < 64; off <<= 1) d += __shfl_xor(d, off, 64);
    if (lane == 0) xtbuf[row] = softcap(d);
}

// ---------------------------------------------------------------------------
// K1: 256x256 8-wave fp8 GEMM at MX rate (K=128/MFMA), 2 windows/tile.
//
// LDS (129+1 KB): Abuf[2] @ {0,32K}, Bbuf[2] @ {64K,96K}, dummy @128K.
// Operand buffer (32KB) = [khalf:2 x16K][row:256 x64B][physslot:4 x16B];
// phys slot p holds logical slot p ^ ((row>>1)&3) (R7-verified involution).
// Fragment read r (r=0,1): ALL 64 lanes read khalf r, slot g^sw of row
// base+li -> per read: 16 rows, 4 lanes/row covering the row's 64B
// contiguously, banks (row&1)*16 + phys*4 — R7's measured-zero pattern.
//
// Staging chunk (1 instr/wave): wave w covers khalf w&1, rows
// ci*64+(w>>1)*16+[0,16), 4 lanes/row, inverse-swizzled source.
// Schedule (verified R9/R11/R12): W0 reads A a(2wr)+all B, issues
// (t+1,a1,a3)->other buf, vmcnt(8); W1 reads A a(2wr+1), issues
// (t+2,b0-3,a0,a2)->current buf, vmcnt(8). ct>=NT -> dummy.
// ---------------------------------------------------------------------------
__device__ __forceinline__ void stage_mx(
    int isB, int ci, int ct, const unsigned char* Asrc, const unsigned char* Bsrc,
    unsigned char* smem, int w, int laneoff)
{
    const int kcol = (ct & (NT - 1)) * BK + (w & 1) * 64;     // khalf per wave
    const int row0 = ci * 64 + (w >> 1) * 16;                 // 16 rows/wave
    const int base = (isB ? 65536 : 0) + (ct & 1) * 32768 + (w & 1) * 16384;
    const int dest = (ct >= NT) ? 131072 : base + row0 * 64;
    const unsigned char* src = (isB ? Bsrc : Asrc) + (size_t)row0 * DIM + kcol + laneoff;
    __builtin_amdgcn_global_load_lds(AS1(src), AS3(smem + dest), 16, 0, 0);
}

// read khalf0 slot g^sw, then khalf1 slot g^sw (+16K) -> one 8-reg tuple
#define LDFRAG(buf, row)                                                       \
    __builtin_shufflevector(*(const i32x4*)((buf) + (row) * 64 + colx),        \
                            *(const i32x4*)((buf) + 16384 + (row) * 64 + colx),\
                            0, 1, 2, 3, 4, 5, 6, 7)

__global__ __launch_bounds__(512, 2) void gemm_mx(
    const unsigned char* __restrict__ A, const unsigned char* __restrict__ B,
    float2* __restrict__ part)
{
    __shared__ unsigned char smem[131072 + 1024] __attribute__((aligned(16)));

    // T1 XCD swizzle: grid 2048 = 8 XCDs x 256; blocks sharing a B panel
    // (16 consecutive bids) land on one XCD's L2.
    const int hw   = blockIdx.x;
    const int bid  = (hw & 7) * 256 + (hw >> 3);
    const int brow = bid & (ROW_TILES - 1);
    const int bcol = bid >> 4;
    const int t0   = threadIdx.x;
    const int lane = t0 & 63;
    const int w    = t0 >> 6;                 // 0..7
    const int wr   = w >> 2;                  // 0..1 (M)
    const int wc   = w & 3;                   // 0..3 (N)
    const int li   = lane & 15;
    const int g    = lane >> 4;               // 0..3 (k-group: k = g*32+[0,32))

    // phys slot for this lane's fragment reads: g ^ ((row>>1)&3), row≡li mod 16
    const int colx = ((g ^ ((li >> 1) & 3)) << 4);

    // staging source (inverse swizzle): lane l covers row_local l>>2,
    // phys slot l&3 -> logical slot (l&3) ^ ((l>>3)&3).
    const int laneoff = (lane >> 2) * DIM + (((lane & 3) ^ ((lane >> 3) & 3)) << 4);

    const unsigned char* Asrc = A + (size_t)brow * BM * DIM;
    const unsigned char* Bsrc = B + (size_t)bcol * BN * DIM;

    f32x4 acc[8][4];
#pragma unroll
    for (int m = 0; m < 8; m++)
#pragma unroll
        for (int n = 0; n < 4; n++) acc[m][n] = (f32x4){0.f, 0.f, 0.f, 0.f};

    // ---- prologue: 14 issues; vmcnt(8) confirms tile0 {b0-3, a0, a2} ----
    stage_mx(1, 0, 0, Asrc, Bsrc, smem, w, laneoff);
    stage_mx(1, 1, 0, Asrc, Bsrc, smem, w, laneoff);
    stage_mx(1, 2, 0, Asrc, Bsrc, smem, w, laneoff);
    stage_mx(1, 3, 0, Asrc, Bsrc, smem, w, laneoff);
    stage_mx(0, 0, 0, Asrc, Bsrc, smem, w, laneoff);
    stage_mx(0, 2, 0, Asrc, Bsrc, smem, w, laneoff);
    stage_mx(0, 1, 0, Asrc, Bsrc, smem, w, laneoff);
    stage_mx(0, 3, 0, Asrc, Bsrc, smem, w, laneoff);
    stage_mx(1, 0, 1, Asrc, Bsrc, smem, w, laneoff);
    stage_mx(1, 1, 1, Asrc, Bsrc, smem, w, laneoff);
    stage_mx(1, 2, 1, Asrc, Bsrc, smem, w, laneoff);
    stage_mx(1, 3, 1, Asrc, Bsrc, smem, w, laneoff);
    stage_mx(0, 0, 1, Asrc, Bsrc, smem, w, laneoff);
    stage_mx(0, 2, 1, Asrc, Bsrc, smem, w, laneoff);
    asm volatile("s_waitcnt vmcnt(8)" ::: "memory");
    __builtin_amdgcn_s_barrier();
    __builtin_amdgcn_sched_barrier(0);

    i32x8 bfr[4];

    for (int t = 0; t < NT; ++t) {
        const int b = t & 1;
        unsigned char* A_rd = smem + b * 32768;
        unsigned char* B_rd = smem + 65536 + b * 32768;

        // ---------------- window 0: acc[0..3] ----------------
        {
#pragma unroll
            for (int n = 0; n < 4; n++)
                bfr[n] = LDFRAG(B_rd, wc * 64 + n * 16 + li);
            stage_mx(0, 1, t + 1, Asrc, Bsrc, smem, w, laneoff);
            stage_mx(0, 3, t + 1, Asrc, Bsrc, smem, w, laneoff);
            __builtin_amdgcn_s_setprio(1);
#pragma unroll
            for (int m = 0; m < 4; m++) {
                i32x8 afr = LDFRAG(A_rd, wr * 128 + m * 16 + li);
                MFMA_F8(acc[m][0], afr, bfr[0]);
                MFMA_F8(acc[m][1], afr, bfr[1]);
                MFMA_F8(acc[m][2], afr, bfr[2]);
                MFMA_F8(acc[m][3], afr, bfr[3]);
            }
            __builtin_amdgcn_s_setprio(0);
            asm volatile("s_waitcnt vmcnt(8)" ::: "memory");
            __builtin_amdgcn_s_barrier();
            __builtin_amdgcn_sched_barrier(0);
        }
        // ---------------- window 1: acc[4..7] ----------------
        {
            stage_mx(1, 0, t + 2, Asrc, Bsrc, smem, w, laneoff);
            stage_mx(1, 1, t + 2, Asrc, Bsrc, smem, w, laneoff);
            stage_mx(1, 2, t + 2, Asrc, Bsrc, smem, w, laneoff);
            stage_mx(1, 3, t + 2, Asrc, Bsrc, smem, w, laneoff);
            stage_mx(0, 0, t + 2, Asrc, Bsrc, smem, w, laneoff);
            stage_mx(0, 2, t + 2, Asrc, Bsrc, smem, w, laneoff);
            __builtin_amdgcn_s_setprio(1);
#pragma unroll
            for (int m = 0; m < 4; m++) {
                i32x8 afr = LDFRAG(A_rd, wr * 128 + 64 + m * 16 + li);
                MFMA_F8(acc[m + 4][0], afr, bfr[0]);
                MFMA_F8(acc[m + 4][1], afr, bfr[1]);
                MFMA_F8(acc[m + 4][2], afr, bfr[2]);
                MFMA_F8(acc[m + 4][3], afr, bfr[3]);
            }
            __builtin_amdgcn_s_setprio(0);
            asm volatile("s_waitcnt vmcnt(8)" ::: "memory");
            __builtin_amdgcn_s_barrier();
            __builtin_amdgcn_sched_barrier(0);
        }
    }

    // ---- epilogue: per-row (sum_exp, sum_logit) over 256 columns ----
    __syncthreads();   // full drain (also retires dummy wrap prefetches)
    // MFMA -> accvgpr_read hazard guard (compiler can't see through the asm)
    asm volatile("s_nop 7\n\ts_nop 7\n\ts_nop 7" :::);
    float* red = (float*)smem;   // [8][128][2] f32 = 8 KB, aliases Abuf0

#pragma unroll
    for (int m = 0; m < 8; m++) {
#pragma unroll
        for (int r = 0; r < 4; r++) {
            float s0 = softcap(acc[m][0][r]);
            float s1 = softcap(acc[m][1][r]);
            float s2 = softcap(acc[m][2][r]);
            float s3 = softcap(acc[m][3][r]);
            float se = __expf(s0) + __expf(s1) + __expf(s2) + __expf(s3);
            float st = s0 + s1 + s2 + s3;
#pragma unroll
            for (int off = 1; off < 16; off <<= 1) {
                se += __shfl_xor(se, off, 64);
                st += __shfl_xor(st, off, 64);
            }
            if (li == 0) {
                int rl = m * 16 + g * 4 + r;          // row within wave's 128
                int base = ((wr * 4 + wc) * 128 + rl) * 2;
                red[base + 0] = se;
                red[base + 1] = st;
            }
        }
    }
    __syncthreads();
    if (t0 < BM) {
        int r   = t0;
        int wr2 = r >> 7;
        int rr  = r & 127;
        float se = 0.f, st = 0.f;
#pragma unroll
        for (int q = 0; q < 4; q++) {
            int bq = ((wr2 * 4 + q) * 128 + rr) * 2;
            se += red[bq + 0];
            st += red[bq + 1];
        }
        part[(size_t)(brow * BM + r) * NCB + bcol] = make_float2(se, st);
    }
}

// ---------------------------------------------------------------------------
// K1 fallback (small ws): reg-staged f32->bf16, 128x128, BK=32.
// ---------------------------------------------------------------------------
__global__ __launch_bounds__(256) void gemm_partial_f32(
    const float* __restrict__ hidden, const float* __restrict__ weight,
    float2* __restrict__ part)
{
    __shared__ unsigned short sA[128 * 32];
    __shared__ unsigned short sB[128 * 32];
    __shared__ float red[4][64][2];

    const int bid  = blockIdx.x;
    const int brow = bid & 31;
    const int bcol = bid >> 5;
    const int t    = threadIdx.x;
    const int lane = t & 63;
    const int w    = t >> 6;
    const int wr   = w >> 1, wc = w & 1;

    const int srow = t >> 1;
    const int scol = (t & 1) * 16;
    const float* gA = hidden + (size_t)(brow * 128 + srow) * DIM + scol;
    const float* gB = weight + (size_t)(bcol * 128 + srow) * DIM + scol;
    unsigned short* wA = &sA[srow * 32 + scol];
    unsigned short* wB = &sB[srow * 32 + scol];

    f32x4 acc[4][4];
#pragma unroll
    for (int m = 0; m < 4; m++)
#pragma unroll
        for (int n = 0; n < 4; n++) acc[m][n] = (f32x4){0.f, 0.f, 0.f, 0.f};

    const unsigned short* pa = &sA[(wr * 64 + (lane & 15)) * 32 + (lane >> 4) * 8];
    const unsigned short* pb = &sB[(wc * 64 + (lane & 15)) * 32 + (lane >> 4) * 8];

    for (int k0 = 0; k0 < DIM; k0 += 32) {
        float4 a0 = *(const float4*)(gA + k0);
        float4 a1 = *(const float4*)(gA + k0 + 4);
        float4 a2 = *(const float4*)(gA + k0 + 8);
        float4 a3 = *(const float4*)(gA + k0 + 12);
        float4 b0 = *(const float4*)(gB + k0);
        float4 b1 = *(const float4*)(gB + k0 + 4);
        float4 b2 = *(const float4*)(gB + k0 + 8);
        float4 b3 = *(const float4*)(gB + k0 + 12);
        __syncthreads();
        u16x8 pa0 = { f2bf(a0.x), f2bf(a0.y), f2bf(a0.z), f2bf(a0.w),
                      f2bf(a1.x), f2bf(a1.y), f2bf(a1.z), f2bf(a1.w) };
        u16x8 pa1 = { f2bf(a2.x), f2bf(a2.y), f2bf(a2.z), f2bf(a2.w),
                      f2bf(a3.x), f2bf(a3.y), f2bf(a3.z), f2bf(a3.w) };
        u16x8 pb0 = { f2bf(b0.x), f2bf(b0.y), f2bf(b0.z), f2bf(b0.w),
                      f2bf(b1.x), f2bf(b1.y), f2bf(b1.z), f2bf(b1.w) };
        u16x8 pb1 = { f2bf(b2.x), f2bf(b2.y), f2bf(b2.z), f2bf(b2.w),
                      f2bf(b3.x), f2bf(b3.y), f2bf(b3.z), f2bf(b3.w) };
        *(u16x8*)wA = pa0;
        *(u16x8*)(wA + 8) = pa1;
        *(u16x8*)wB = pb0;
        *(u16x8*)(wB + 8) = pb1;
        __syncthreads();

        s16x8 afr[4], bfr[4];
#pragma unroll
        for (int m = 0; m < 4; m++) afr[m] = *(const s16x8*)(pa + m * 16 * 32);
#pragma unroll
        for (int n = 0; n < 4; n++) bfr[n] = *(const s16x8*)(pb + n * 16 * 32);
#pragma unroll
        for (int m = 0; m < 4; m++)
#pragma unroll
            for (int n = 0; n < 4; n++)
                acc[m][n] = __builtin_amdgcn_mfma_f32_16x16x32_bf16(
                    afr[m], bfr[n], acc[m][n], 0, 0, 0);
    }

    const int g  = lane >> 4;
    const int li = lane & 15;
#pragma unroll
    for (int m = 0; m < 4; m++) {
#pragma unroll
        for (int r = 0; r < 4; r++) {
            float s0 = softcap(acc[m][0][r]);
            float s1 = softcap(acc[m][1][r]);
            float s2 = softcap(acc[m][2][r]);
            float s3 = softcap(acc[m][3][r]);
            float se = __expf(s0) + __expf(s1) + __expf(s2) + __expf(s3);
            float st = s0 + s1 + s2 + s3;
#pragma unroll
            for (int off = 1; off < 16; off <<= 1) {
                se += __shfl_xor(se, off, 64);
                st += __shfl_xor(st, off, 64);
            }
            if (li == 0) {
                int rl = m * 16 + g * 4 + r;
                red[w][rl][0] = se;
                red[w][rl][1] = st;
            }
        }
    }
    __syncthreads();
    if (t < 128) {
        int r  = t;
        int wa = (r >> 6) * 2;
        int rr = r & 63;
        float se = red[wa][rr][0] + red[wa + 1][rr][0];
        float st = red[wa][rr][1] + red[wa + 1][rr][1];
        part[(size_t)(brow * 128 + r) * 256 + bcol] = make_float2(se, st);
    }
}

// ---------------------------------------------------------------------------
// K2: sum ncb column-block partials per row. 1 wave/row.
// ---------------------------------------------------------------------------
__global__ __launch_bounds__(256) void row_reduce(
    const float2* __restrict__ part, const int* __restrict__ targets,
    const float* __restrict__ xtbuf, float* __restrict__ rowbuf, int ncb)
{
    int row  = blockIdx.x * 4 + (threadIdx.x >> 6);
    int lane = threadIdx.x & 63;
    if (row >= N_ROWS) return;
    const float2* p = part + (size_t)row * ncb;
    float se = 0.f, st = 0.f;
    for (int q = lane; q < ncb; q += 64) {
        float2 u = p[q];
        se += u.x;
        st += u.y;
    }
#pragma unroll
    for (int off = 1; off < 64; off <<= 1) {
        se += __shfl_xor(se, off, 64);
        st += __shfl_xor(st, off, 64);
    }
    if (lane == 0) {
        float lse = logf(se);
        int   tgt = targets[row];
        float vf  = (tgt != IGNORE_IDX) ? 1.f : 0.f;
        float xt  = xtbuf[row];
        float nll = lse - xt;
        float smooth = lse - st * (1.f / (float)VOCAB);
        float rl = 0.9f * nll + 0.1f * smooth;
        rowbuf[row * 3 + 0] = rl * vf;
        rowbuf[row * 3 + 1] = lse * lse * vf;
        rowbuf[row * 3 + 2] = vf;
    }
}

// ---------------------------------------------------------------------------
// K3: deterministic final reduction -> scalar loss.
// ---------------------------------------------------------------------------
__global__ __launch_bounds__(256) void final_reduce(
    const float* __restrict__ rowbuf, float* __restrict__ out)
{
    __shared__ float sl[256], sz[256], sv[256];
    int t = threadIdx.x;
    float ls = 0.f, zs = 0.f, vs = 0.f;
    for (int r = t; r < N_ROWS; r += 256) {
        ls += rowbuf[r * 3 + 0];
        zs += rowbuf[r * 3 + 1];
        vs += rowbuf[r * 3 + 2];
    }
    sl[t] = ls; sz[t] = zs; sv[t] = vs;
    __syncthreads();
    for (int o = 128; o > 0; o >>= 1) {
        if (t < o) { sl[t] += sl[t + o]; sz[t] += sz[t + o]; sv[t] += sv[t + o]; }
        __syncthreads();
    }
    if (t == 0) {
        float nv = fmaxf(sv[0], 1.f);
        out[0] = sl[0] / nv + 1e-4f * (sz[0] / nv);
    }
}

// ---------------------------------------------------------------------------
extern "C" void kernel_launch(void* const* d_in, const int* in_sizes, int n_in,
                              void* d_out, int out_size, void* d_ws, size_t ws_size,
                              hipStream_t stream)
{
    const float* hidden  = (const float*)d_in[0];
    const float* weight  = (const float*)d_in[1];
    const int*   targets = (const int*)d_in[2];
    float*       out     = (float*)d_out;

    char* ws = (char*)d_ws;
    size_t off = 0;
    float2* part = (float2*)(ws + off);
    off += (size_t)N_ROWS * 256 * sizeof(float4);           // 16 MB slot (max layout)
    float* xtbuf = (float*)(ws + off);
    off += (size_t)N_ROWS * sizeof(float);
    float* rowbuf = (float*)(ws + off);
    off += (size_t)N_ROWS * 3 * sizeof(float);
    off = (off + 255) & ~(size_t)255;
    unsigned char* hid8 = (unsigned char*)(ws + off);
    off += (size_t)N_ROWS * DIM;                            // 8 MB
    unsigned char* wgt8 = (unsigned char*)(ws + off);
    off += (size_t)VOCAB * DIM;                             // 67 MB

    target_logit<<<N_ROWS / 4, 256, 0, stream>>>(hidden, weight, targets, xtbuf);

    if (ws_size >= off) {
        convert_fp8<<<2048, 256, 0, stream>>>(hidden, hid8, N_ROWS * (DIM / 16));
        convert_fp8<<<2048, 256, 0, stream>>>(weight, wgt8, VOCAB * (DIM / 16));
        gemm_mx<<<ROW_TILES * (VOCAB / BN), 512, 0, stream>>>(hid8, wgt8, part);
        row_reduce<<<N_ROWS / 4, 256, 0, stream>>>(part, targets, xtbuf, rowbuf, NCB);
    } else {
        gemm_partial_f32<<<32 * 256, 256, 0, stream>>>(hidden, weight, part);
        row_reduce<<<N_ROWS / 4, 256, 0, stream>>>(part, targets, xtbuf, rowbuf, 256);
    }

    final_reduce<<<1, 256, 0, stream>>>(rowbuf, out);
}